// Round 1
// baseline (1449.400 us; speedup 1.0000x reference)
//
#include <hip/hip_runtime.h>
#include <math.h>

#define N_NODES 20000
#define N_EDGES 200000
#define NDIM 128
#define EDIM 64
#define HDIM 256
#define HEADS 4
#define NH 1024      // HEADS*HDIM
#define NLAYERS 3

__device__ __forceinline__ float wave_reduce_sum(float v) {
    #pragma unroll
    for (int off = 32; off > 0; off >>= 1) v += __shfl_down(v, off, 64);
    return v;
}

// ---------------- CSR build ----------------
__global__ void hist_kernel(const int* __restrict__ dst0, int* __restrict__ cnt) {
    int e = blockIdx.x * 256 + threadIdx.x;
    if (e < N_EDGES) atomicAdd(&cnt[dst0[e]], 1);
}

__global__ void scan_kernel(const int* __restrict__ cnt, int* __restrict__ row_ptr) {
    __shared__ int sh[256];
    __shared__ int carry_sh;
    int tid = threadIdx.x;
    if (tid == 0) carry_sh = 0;
    __syncthreads();
    for (int base = 0; base < N_NODES; base += 256) {
        int v = (base + tid < N_NODES) ? cnt[base + tid] : 0;
        sh[tid] = v;
        __syncthreads();
        for (int off = 1; off < 256; off <<= 1) {
            int t = (tid >= off) ? sh[tid - off] : 0;
            __syncthreads();
            sh[tid] += t;
            __syncthreads();
        }
        int incl = sh[tid];
        int carry = carry_sh;
        if (base + tid < N_NODES) row_ptr[base + tid] = carry + incl - v;
        __syncthreads();
        if (tid == 255) carry_sh = carry + incl;
        __syncthreads();
    }
    if (tid == 0) row_ptr[N_NODES] = carry_sh;
}

__global__ void fill_kernel(const int* __restrict__ dst0, const int* __restrict__ row_ptr,
                            int* __restrict__ fillc, int* __restrict__ edge_ids) {
    int e = blockIdx.x * 256 + threadIdx.x;
    if (e < N_EDGES) {
        int d = dst0[e];
        int p = atomicAdd(&fillc[d], 1);
        edge_ids[row_ptr[d] + p] = e;
    }
}

// ---------------- generic fp32 GEMM: C = op(A[M,K] @ B[K,N] + bias) ----------------
#define BM 128
#define BN 128
#define BK 16

template <bool RELU, bool BIAS>
__global__ __launch_bounds__(256) void gemm_f32(
    const float* __restrict__ A, const float* __restrict__ B,
    const float* __restrict__ bias, float* __restrict__ C,
    int M, int N, int K)
{
    __shared__ float As[BK][BM + 4];
    __shared__ float Bs[BK][BN + 4];
    int tid = threadIdx.x;
    int rowBase = blockIdx.y * BM;
    int colBase = blockIdx.x * BN;
    int ty4 = (tid >> 4) * 4;
    int tx4 = (tid & 15) * 4;
    int ar = tid >> 2;             // 0..63
    int ac = (tid & 3) * 4;        // 0,4,8,12
    int bkr = tid >> 4;            // 0..15
    int bc = (tid & 15) * 4;       // 0..60

    float acc[8][8] = {};

    for (int k0 = 0; k0 < K; k0 += BK) {
        #pragma unroll
        for (int half = 0; half < 2; half++) {
            int r = ar + half * 64;
            int grow = rowBase + r;
            float4 av = make_float4(0.f, 0.f, 0.f, 0.f);
            if (grow < M) av = *(const float4*)(A + (size_t)grow * K + k0 + ac);
            As[ac + 0][r] = av.x; As[ac + 1][r] = av.y;
            As[ac + 2][r] = av.z; As[ac + 3][r] = av.w;
        }
        #pragma unroll
        for (int half = 0; half < 2; half++) {
            int c = bc + half * 64;
            float4 bv = *(const float4*)(B + (size_t)(k0 + bkr) * N + colBase + c);
            *(float4*)(&Bs[bkr][c]) = bv;
        }
        __syncthreads();
        #pragma unroll
        for (int kk = 0; kk < BK; kk++) {
            float4 a0 = *(const float4*)(&As[kk][ty4]);
            float4 a1 = *(const float4*)(&As[kk][ty4 + 64]);
            float4 b0 = *(const float4*)(&Bs[kk][tx4]);
            float4 b1 = *(const float4*)(&Bs[kk][tx4 + 64]);
            float av[8] = {a0.x, a0.y, a0.z, a0.w, a1.x, a1.y, a1.z, a1.w};
            float bv[8] = {b0.x, b0.y, b0.z, b0.w, b1.x, b1.y, b1.z, b1.w};
            #pragma unroll
            for (int i = 0; i < 8; i++)
                #pragma unroll
                for (int j = 0; j < 8; j++)
                    acc[i][j] += av[i] * bv[j];
        }
        __syncthreads();
    }

    #pragma unroll
    for (int i = 0; i < 8; i++) {
        int row = rowBase + (i < 4 ? ty4 + i : 64 + ty4 + i - 4);
        if (row >= M) continue;
        #pragma unroll
        for (int jh = 0; jh < 2; jh++) {
            int col = colBase + jh * 64 + tx4;
            float4 r = make_float4(acc[i][jh * 4 + 0], acc[i][jh * 4 + 1],
                                   acc[i][jh * 4 + 2], acc[i][jh * 4 + 3]);
            if (BIAS) {
                r.x += bias[col]; r.y += bias[col + 1];
                r.z += bias[col + 2]; r.w += bias[col + 3];
            }
            if (RELU) {
                r.x = fmaxf(r.x, 0.f); r.y = fmaxf(r.y, 0.f);
                r.z = fmaxf(r.z, 0.f); r.w = fmaxf(r.w, 0.f);
            }
            *(float4*)(C + (size_t)row * N + col) = r;
        }
    }
}

// ---------------- per-layer small precompute ----------------
// wmean[j] = mean_d edge_enc_w[l][j,d]; scal[0..3]=c[h]; scal[4]=mean(edge_enc_b[l])
__global__ void layer_prep(const float* __restrict__ eew, const float* __restrict__ eeb,
                           const float* __restrict__ lew, const float* __restrict__ ae,
                           float* __restrict__ wmean, float* __restrict__ scal)
{
    int tid = threadIdx.x;
    if (tid < 64) {
        float s = 0.f;
        for (int d = 0; d < HDIM; d++) s += eew[tid * HDIM + d];
        wmean[tid] = s * (1.f / HDIM);
    } else if (tid < 68) {
        int h = tid - 64;
        float s = 0.f;
        for (int d = 0; d < HDIM; d++) s += lew[h * HDIM + d] * ae[h * HDIM + d];
        scal[h] = s;
    } else if (tid == 68) {
        float s = 0.f;
        for (int d = 0; d < HDIM; d++) s += eeb[d];
        scal[4] = s * (1.f / HDIM);
    }
}

// ew[e] = dot(edge_attr[e,:], wmean) + bmean   (one wave per edge)
__global__ __launch_bounds__(256) void edge_weights(const float* __restrict__ edge_attr,
                                                    const float* __restrict__ wmean,
                                                    const float* __restrict__ scal,
                                                    float* __restrict__ ew)
{
    int e = blockIdx.x * 4 + (threadIdx.x >> 6);
    int lane = threadIdx.x & 63;
    if (e >= N_EDGES) return;
    float v = edge_attr[(size_t)e * EDIM + lane] * wmean[lane];
    v = wave_reduce_sum(v);
    if (lane == 0) ew[e] = v + scal[4];
}

__global__ void loop_weights(const float* __restrict__ ew, const int* __restrict__ row_ptr,
                             const int* __restrict__ edge_ids, float* __restrict__ loopw)
{
    int n = blockIdx.x * 256 + threadIdx.x;
    if (n >= N_NODES) return;
    int r0 = row_ptr[n], r1 = row_ptr[n + 1];
    float s = 0.f;
    for (int i = r0; i < r1; i++) s += ew[edge_ids[i]];
    float dg = (float)(r1 - r0);
    loopw[n] = s / fmaxf(dg, 1.f);
}

// a_s[n,h] = <xp[n,h,:], att_src[h,:]>, a_d likewise. One block per node, wave h per head.
__global__ __launch_bounds__(256) void attn_coef(const float* __restrict__ xp,
                                                 const float* __restrict__ att_s,
                                                 const float* __restrict__ att_d,
                                                 float* __restrict__ a_s,
                                                 float* __restrict__ a_d)
{
    int n = blockIdx.x;
    int h = threadIdx.x >> 6;
    int lane = threadIdx.x & 63;
    const float* xr = xp + (size_t)n * NH + h * HDIM;
    float ss = 0.f, sd = 0.f;
    #pragma unroll
    for (int j = 0; j < 4; j++) {
        float v = xr[lane + j * 64];
        ss += v * att_s[h * HDIM + lane + j * 64];
        sd += v * att_d[h * HDIM + lane + j * 64];
    }
    ss = wave_reduce_sum(ss);
    sd = wave_reduce_sum(sd);
    if (lane == 0) { a_s[n * 4 + h] = ss; a_d[n * 4 + h] = sd; }
}

// Fused: per-node segment softmax over incoming edges (+self loop), aggregate,
// head-mean + bias, LayerNorm, residual ReLU, in-place x update.
__global__ __launch_bounds__(256) void gat_aggregate_ln(
    const float* __restrict__ xp, const float* __restrict__ a_s,
    const float* __restrict__ a_d, const float* __restrict__ ew,
    const float* __restrict__ loopw, const float* __restrict__ scal,
    const int* __restrict__ row_ptr, const int* __restrict__ edge_ids,
    const int* __restrict__ src0,
    const float* __restrict__ gat_b, const float* __restrict__ ln_g,
    const float* __restrict__ ln_b, float* __restrict__ x)
{
    int n = blockIdx.x;
    int tid = threadIdx.x;
    int r0 = row_ptr[n], r1 = row_ptr[n + 1];
    int deg = r1 - r0;
    int cnt = deg + 1;   // + self loop

    __shared__ float4 red4[256];
    __shared__ float m_sh[4], s_sh[4], c_sh[4], ad_sh[4];
    __shared__ float p_ch[64 * 4];
    __shared__ int src_ch[64];

    if (tid < 4) { c_sh[tid] = scal[tid]; ad_sh[tid] = a_d[n * 4 + tid]; }
    __syncthreads();

    // pass 1: per-head max of leaky_relu logits
    float tmax[4] = {-1e30f, -1e30f, -1e30f, -1e30f};
    for (int idx = tid; idx < cnt; idx += 256) {
        int sn; float w;
        if (idx < deg) { int e = edge_ids[r0 + idx]; sn = src0[e]; w = ew[e]; }
        else           { sn = n; w = loopw[n]; }
        #pragma unroll
        for (int h = 0; h < 4; h++) {
            float z = a_s[sn * 4 + h] + ad_sh[h] + c_sh[h] * w;
            z = z > 0.f ? z : 0.2f * z;
            tmax[h] = fmaxf(tmax[h], z);
        }
    }
    red4[tid] = make_float4(tmax[0], tmax[1], tmax[2], tmax[3]);
    __syncthreads();
    for (int off = 128; off > 0; off >>= 1) {
        if (tid < off) {
            float4 a = red4[tid], b = red4[tid + off];
            a.x = fmaxf(a.x, b.x); a.y = fmaxf(a.y, b.y);
            a.z = fmaxf(a.z, b.z); a.w = fmaxf(a.w, b.w);
            red4[tid] = a;
        }
        __syncthreads();
    }
    if (tid == 0) {
        float4 m = red4[0];
        m_sh[0] = m.x; m_sh[1] = m.y; m_sh[2] = m.z; m_sh[3] = m.w;
    }
    __syncthreads();

    // pass 2: per-head sum of exp(z - m)
    float tsum[4] = {0.f, 0.f, 0.f, 0.f};
    for (int idx = tid; idx < cnt; idx += 256) {
        int sn; float w;
        if (idx < deg) { int e = edge_ids[r0 + idx]; sn = src0[e]; w = ew[e]; }
        else           { sn = n; w = loopw[n]; }
        #pragma unroll
        for (int h = 0; h < 4; h++) {
            float z = a_s[sn * 4 + h] + ad_sh[h] + c_sh[h] * w;
            z = z > 0.f ? z : 0.2f * z;
            tsum[h] += expf(z - m_sh[h]);
        }
    }
    red4[tid] = make_float4(tsum[0], tsum[1], tsum[2], tsum[3]);
    __syncthreads();
    for (int off = 128; off > 0; off >>= 1) {
        if (tid < off) {
            float4 a = red4[tid], b = red4[tid + off];
            a.x += b.x; a.y += b.y; a.z += b.z; a.w += b.w;
            red4[tid] = a;
        }
        __syncthreads();
    }
    if (tid == 0) {
        float4 s = red4[0];
        s_sh[0] = s.x; s_sh[1] = s.y; s_sh[2] = s.z; s_sh[3] = s.w;
    }
    __syncthreads();

    // pass 3: weighted aggregation (alpha already normalized), chunked over edges
    float acc = 0.f;
    int d = tid;
    for (int base = 0; base < cnt; base += 64) {
        int m = min(64, cnt - base);
        if (tid < m) {
            int idx = base + tid; int sn; float w;
            if (idx < deg) { int e = edge_ids[r0 + idx]; sn = src0[e]; w = ew[e]; }
            else           { sn = n; w = loopw[n]; }
            src_ch[tid] = sn;
            #pragma unroll
            for (int h = 0; h < 4; h++) {
                float z = a_s[sn * 4 + h] + ad_sh[h] + c_sh[h] * w;
                z = z > 0.f ? z : 0.2f * z;
                p_ch[tid * 4 + h] = expf(z - m_sh[h]) / s_sh[h];
            }
        }
        __syncthreads();
        for (int j = 0; j < m; j++) {
            const float* xr = xp + (size_t)src_ch[j] * NH + d;
            acc += p_ch[j * 4 + 0] * xr[0]
                 + p_ch[j * 4 + 1] * xr[256]
                 + p_ch[j * 4 + 2] * xr[512]
                 + p_ch[j * 4 + 3] * xr[768];
        }
        __syncthreads();
    }

    float y = acc * 0.25f + gat_b[d];

    // LayerNorm over d (256 values, one per thread)
    red4[tid].x = y;
    __syncthreads();
    for (int off = 128; off > 0; off >>= 1) {
        if (tid < off) red4[tid].x += red4[tid + off].x;
        __syncthreads();
    }
    float mu = red4[0].x * (1.f / HDIM);
    __syncthreads();
    float dev = y - mu;
    red4[tid].x = dev * dev;
    __syncthreads();
    for (int off = 128; off > 0; off >>= 1) {
        if (tid < off) red4[tid].x += red4[tid + off].x;
        __syncthreads();
    }
    float var = red4[0].x * (1.f / HDIM);
    float xn = ln_g[d] * dev * rsqrtf(var + 1e-5f) + ln_b[d];
    float xo = x[(size_t)n * HDIM + d];
    x[(size_t)n * HDIM + d] = fmaxf(xo + xn, 0.f);
}

// head second layer: o[k,n] = dot(hmid[k,n,:], w2[k,:]) + b2[k]; sigmoid on k=0,3
__global__ __launch_bounds__(256) void head2_kernel(const float* __restrict__ hmid,
                                                    const float* __restrict__ w2,
                                                    const float* __restrict__ b2,
                                                    float* __restrict__ out)
{
    int gw = blockIdx.x * 4 + (threadIdx.x >> 6);
    int lane = threadIdx.x & 63;
    int n = gw >> 2;
    int k = gw & 3;
    if (n >= N_NODES) return;
    const float* hr = hmid + (size_t)k * N_NODES * 128 + (size_t)n * 128;
    const float* wr = w2 + k * 128;
    float s = hr[lane] * wr[lane] + hr[lane + 64] * wr[lane + 64];
    s = wave_reduce_sum(s);
    if (lane == 0) {
        s += b2[k];
        if (k == 0 || k == 3) s = 1.f / (1.f + expf(-s));
        out[k * N_NODES + n] = s;
    }
}

__global__ void copy_emb(const float* __restrict__ x, float* __restrict__ out) {
    int i = blockIdx.x * 256 + threadIdx.x;
    ((float4*)out)[i] = ((const float4*)x)[i];
}

extern "C" void kernel_launch(void* const* d_in, const int* in_sizes, int n_in,
                              void* d_out, int out_size, void* d_ws, size_t ws_size,
                              hipStream_t stream) {
    const float* node_features = (const float*)d_in[0];
    const float* edge_attr     = (const float*)d_in[1];
    const float* enc_w         = (const float*)d_in[2];
    const float* enc_b         = (const float*)d_in[3];
    const float* edge_enc_w    = (const float*)d_in[4];
    const float* edge_enc_b    = (const float*)d_in[5];
    const float* gat_w         = (const float*)d_in[6];
    const float* att_src       = (const float*)d_in[7];
    const float* att_dst       = (const float*)d_in[8];
    const float* att_edge      = (const float*)d_in[9];
    const float* lin_edge_w    = (const float*)d_in[10];
    const float* gat_b         = (const float*)d_in[11];
    const float* ln_g          = (const float*)d_in[12];
    const float* ln_b          = (const float*)d_in[13];
    const float* head_w1       = (const float*)d_in[14];
    const float* head_b1       = (const float*)d_in[15];
    const float* head_w2       = (const float*)d_in[16];
    const float* head_b2       = (const float*)d_in[17];
    const int*   edge_index    = (const int*)d_in[18];
    const int* src0 = edge_index;
    const int* dst0 = edge_index + N_EDGES;
    float* out = (float*)d_out;

    // workspace layout
    float* x      = (float*)d_ws;                        // N*H
    float* xp     = x + (size_t)N_NODES * HDIM;          // N*NH
    float* a_s    = xp + (size_t)N_NODES * NH;           // N*4
    float* a_d    = a_s + N_NODES * HEADS;               // N*4
    float* ew     = a_d + N_NODES * HEADS;               // E
    float* loopw  = ew + N_EDGES;                        // N
    float* wmean  = loopw + N_NODES;                     // 64
    float* scal   = wmean + 64;                          // 8
    int* cnt      = (int*)(scal + 8);                    // N
    int* fillc    = cnt + N_NODES;                       // N
    int* row_ptr  = fillc + N_NODES;                     // N+1
    int* edge_ids = row_ptr + (N_NODES + 1);             // E
    float* hmid   = xp;                                  // reuse xp region (4*N*128 <= N*NH)

    // zero histogram + fill counters
    hipMemsetAsync(cnt, 0, 2 * N_NODES * sizeof(int), stream);

    // CSR build (by dst)
    hist_kernel<<<(N_EDGES + 255) / 256, 256, 0, stream>>>(dst0, cnt);
    scan_kernel<<<1, 256, 0, stream>>>(cnt, row_ptr);
    fill_kernel<<<(N_EDGES + 255) / 256, 256, 0, stream>>>(dst0, row_ptr, fillc, edge_ids);

    // encoder: x = relu(nf @ enc_w + enc_b)
    {
        dim3 grid(HDIM / BN, (N_NODES + BM - 1) / BM);
        gemm_f32<true, true><<<grid, 256, 0, stream>>>(node_features, enc_w, enc_b, x,
                                                       N_NODES, HDIM, NDIM);
    }

    for (int l = 0; l < NLAYERS; l++) {
        layer_prep<<<1, 128, 0, stream>>>(edge_enc_w + (size_t)l * EDIM * HDIM,
                                          edge_enc_b + (size_t)l * HDIM,
                                          lin_edge_w + (size_t)l * NH,
                                          att_edge + (size_t)l * NH,
                                          wmean, scal);
        edge_weights<<<N_EDGES / 4, 256, 0, stream>>>(edge_attr, wmean, scal, ew);
        loop_weights<<<(N_NODES + 255) / 256, 256, 0, stream>>>(ew, row_ptr, edge_ids, loopw);
        {
            dim3 grid(NH / BN, (N_NODES + BM - 1) / BM);
            gemm_f32<false, false><<<grid, 256, 0, stream>>>(x, gat_w + (size_t)l * HDIM * NH,
                                                             nullptr, xp, N_NODES, NH, HDIM);
        }
        attn_coef<<<N_NODES, 256, 0, stream>>>(xp, att_src + (size_t)l * NH,
                                               att_dst + (size_t)l * NH, a_s, a_d);
        gat_aggregate_ln<<<N_NODES, 256, 0, stream>>>(xp, a_s, a_d, ew, loopw, scal,
                                                      row_ptr, edge_ids, src0,
                                                      gat_b + (size_t)l * HDIM,
                                                      ln_g + (size_t)l * HDIM,
                                                      ln_b + (size_t)l * HDIM, x);
    }

    // prediction heads: hmid[k] = relu(x @ head_w1[k] + head_b1[k])
    for (int k = 0; k < 4; k++) {
        dim3 grid(128 / BN + (128 % BN ? 1 : 0), (N_NODES + BM - 1) / BM);
        gemm_f32<true, true><<<dim3(1, (N_NODES + BM - 1) / BM), 256, 0, stream>>>(
            x, head_w1 + (size_t)k * HDIM * 128, head_b1 + (size_t)k * 128,
            hmid + (size_t)k * N_NODES * 128, N_NODES, 128, HDIM);
    }
    head2_kernel<<<N_NODES, 256, 0, stream>>>(hmid, head_w2, head_b2, out);

    // emb output at offset 4*N
    copy_emb<<<(N_NODES * HDIM / 4) / 256, 256, 0, stream>>>(x, out + 4 * N_NODES);
}

// Round 3
// 735.105 us; speedup vs baseline: 1.9717x; 1.9717x over previous
//
#include <hip/hip_runtime.h>
#include <math.h>

#define N_NODES 20000
#define N_EDGES 200000
#define NDIM 128
#define EDIM 64
#define HDIM 256
#define HEADS 4
#define NH 1024
#define NLAYERS 3

typedef __attribute__((ext_vector_type(8))) short short8;
typedef __attribute__((ext_vector_type(4))) float floatx4;

__device__ __forceinline__ float b2f(unsigned short u) {
    union { unsigned u; float f; } c; c.u = ((unsigned)u) << 16; return c.f;
}
__device__ __forceinline__ unsigned short f2b(float f) {
    union { float f; unsigned u; } c; c.f = f;
    unsigned u = c.u;
    return (unsigned short)((u + 0x7FFFu + ((u >> 16) & 1u)) >> 16);
}

__device__ __forceinline__ float wave_reduce_sum(float v) {
    #pragma unroll
    for (int off = 32; off > 0; off >>= 1) v += __shfl_down(v, off, 64);
    return v;
}

// ---------------- CSR build ----------------
__global__ void hist_kernel(const int* __restrict__ dst0, int* __restrict__ cnt) {
    int e = blockIdx.x * 256 + threadIdx.x;
    if (e < N_EDGES) atomicAdd(&cnt[dst0[e]], 1);
}

__global__ void scan_kernel(const int* __restrict__ cnt, int* __restrict__ row_ptr) {
    __shared__ int wsum[4];
    __shared__ int carry_sh;
    int tid = threadIdx.x, lane = tid & 63, wid = tid >> 6;
    if (tid == 0) carry_sh = 0;
    __syncthreads();
    for (int base = 0; base < N_NODES; base += 256) {
        int v = (base + tid < N_NODES) ? cnt[base + tid] : 0;
        int s = v;
        #pragma unroll
        for (int off = 1; off < 64; off <<= 1) {
            int t = __shfl_up(s, off, 64);
            if (lane >= off) s += t;
        }
        if (lane == 63) wsum[wid] = s;
        int carry = carry_sh;
        __syncthreads();
        int woff = 0;
        for (int w = 0; w < wid; w++) woff += wsum[w];
        int incl = s + woff;
        if (base + tid < N_NODES) row_ptr[base + tid] = carry + incl - v;
        __syncthreads();
        if (tid == 255) carry_sh = carry + incl;
        __syncthreads();
    }
    if (tid == 0) row_ptr[N_NODES] = carry_sh;
}

__global__ void fill_kernel(const int* __restrict__ dst0, const int* __restrict__ row_ptr,
                            int* __restrict__ fillc, int* __restrict__ edge_ids) {
    int e = blockIdx.x * 256 + threadIdx.x;
    if (e < N_EDGES) {
        int d = dst0[e];
        int p = atomicAdd(&fillc[d], 1);
        edge_ids[row_ptr[d] + p] = e;
    }
}

// ---------------- weight prep ----------------
// fp32 in [K][Nn] -> bf16 out [Nn][K], batched via blockIdx.z
__global__ void transpose_bf(const float* __restrict__ in, unsigned short* __restrict__ out,
                             int K, int Nn, size_t in_bs, size_t out_bs) {
    in += blockIdx.z * in_bs;
    out += blockIdx.z * out_bs;
    __shared__ float sh[32][33];
    int tx = threadIdx.x, ty = threadIdx.y;
    int kb = blockIdx.y * 32, nb = blockIdx.x * 32;
    #pragma unroll
    for (int i = 0; i < 32; i += 8)
        sh[ty + i][tx] = in[(size_t)(kb + ty + i) * Nn + nb + tx];
    __syncthreads();
    #pragma unroll
    for (int i = 0; i < 32; i += 8)
        out[(size_t)(nb + ty + i) * K + kb + tx] = f2b(sh[tx][ty + i]);
}

__global__ void conv_bf(const float* __restrict__ in, unsigned short* __restrict__ out) {
    int i = blockIdx.x * 256 + threadIdx.x;
    float4 v = ((const float4*)in)[i];
    ushort4 o;
    o.x = f2b(v.x); o.y = f2b(v.y); o.z = f2b(v.z); o.w = f2b(v.w);
    ((ushort4*)out)[i] = o;
}

// ---------------- bf16 MFMA GEMM: C[M,Ntot] = op(A[M,K] @ Bt[Ntot,K]^T + bias) ----------------
template <bool RELU, bool BIAS>
__global__ __launch_bounds__(256) void gemm_bf16(
    const unsigned short* __restrict__ A, const unsigned short* __restrict__ Bt,
    const float* __restrict__ bias, unsigned short* __restrict__ C,
    int M, int Ntot, int K)
{
    __shared__ char lds[32768];
    unsigned short* As = (unsigned short*)lds;           // [128][32]
    unsigned short* Bs = (unsigned short*)(lds + 8192);  // [128][32]
    unsigned short* Cs = (unsigned short*)lds;           // [128][128] (after K loop)

    int tid = threadIdx.x;
    int lane = tid & 63;
    int wid = tid >> 6;
    int row0 = blockIdx.y * 128;
    int col0 = blockIdx.x * 128;
    int wm = (wid >> 1) * 64;
    int wn = (wid & 1) * 64;
    int lm = lane & 15;
    int q8 = (lane >> 4) * 8;
    int q4 = (lane >> 4) * 4;

    floatx4 acc[4][4];
    #pragma unroll
    for (int i = 0; i < 4; i++)
        #pragma unroll
        for (int j = 0; j < 4; j++)
            acc[i][j] = (floatx4)(0.f);

    for (int k0 = 0; k0 < K; k0 += 32) {
        #pragma unroll
        for (int r = 0; r < 2; r++) {
            int chunk = tid + r * 256;
            int arow = chunk >> 2;
            int acol = (chunk & 3) * 8;
            int garow = row0 + arow; if (garow > M - 1) garow = M - 1;
            __builtin_amdgcn_global_load_lds(
                (__attribute__((address_space(1))) const void*)(A + (size_t)garow * K + k0 + acol),
                (__attribute__((address_space(3))) void*)(As + chunk * 8), 16, 0, 0);
            __builtin_amdgcn_global_load_lds(
                (__attribute__((address_space(1))) const void*)(Bt + (size_t)(col0 + arow) * K + k0 + acol),
                (__attribute__((address_space(3))) void*)(Bs + chunk * 8), 16, 0, 0);
        }
        __syncthreads();
        short8 af[4], bf[4];
        #pragma unroll
        for (int i = 0; i < 4; i++)
            af[i] = *(const short8*)(As + (wm + i * 16 + lm) * 32 + q8);
        #pragma unroll
        for (int j = 0; j < 4; j++)
            bf[j] = *(const short8*)(Bs + (wn + j * 16 + lm) * 32 + q8);
        #pragma unroll
        for (int i = 0; i < 4; i++)
            #pragma unroll
            for (int j = 0; j < 4; j++)
                acc[i][j] = __builtin_amdgcn_mfma_f32_16x16x32_bf16(af[i], bf[j], acc[i][j], 0, 0, 0);
        __syncthreads();
    }

    // epilogue: acc -> bf16 via LDS, then coalesced 16B stores
    #pragma unroll
    for (int i = 0; i < 4; i++) {
        #pragma unroll
        for (int j = 0; j < 4; j++) {
            int cl = wn + j * 16 + lm;
            float bv = BIAS ? bias[col0 + cl] : 0.f;
            #pragma unroll
            for (int reg = 0; reg < 4; reg++) {
                int rl = wm + i * 16 + q4 + reg;
                float v = acc[i][j][reg];
                if (BIAS) v += bv;
                if (RELU) v = fmaxf(v, 0.f);
                Cs[rl * 128 + cl] = f2b(v);
            }
        }
    }
    __syncthreads();
    int row = tid >> 1;
    int ce = (tid & 1) * 64;
    if (row0 + row < M) {
        #pragma unroll
        for (int u = 0; u < 8; u++) {
            int4 v = *(const int4*)(Cs + row * 128 + ce + u * 8);
            *(int4*)(C + (size_t)(row0 + row) * Ntot + col0 + ce + u * 8) = v;
        }
    }
}

// ---------------- per-layer small precompute (all 3 layers) ----------------
__global__ void layer_prep3(const float* __restrict__ edge_enc_w, const float* __restrict__ edge_enc_b,
                            const float* __restrict__ lin_edge_w, const float* __restrict__ att_edge,
                            float* __restrict__ wmean3, float* __restrict__ scal3)
{
    int l = blockIdx.x;
    const float* eew = edge_enc_w + (size_t)l * EDIM * HDIM;
    const float* eeb = edge_enc_b + (size_t)l * HDIM;
    const float* lew = lin_edge_w + (size_t)l * NH;
    const float* ae  = att_edge + (size_t)l * NH;
    float* wm = wmean3 + l * 64;
    float* sc = scal3 + l * 8;
    int tid = threadIdx.x;
    if (tid < 64) {
        float s = 0.f;
        for (int d = 0; d < HDIM; d++) s += eew[tid * HDIM + d];
        wm[tid] = s * (1.f / HDIM);
    } else if (tid < 68) {
        int h = tid - 64;
        float s = 0.f;
        for (int d = 0; d < HDIM; d++) s += lew[h * HDIM + d] * ae[h * HDIM + d];
        sc[h] = s;
    } else if (tid == 68) {
        float s = 0.f;
        for (int d = 0; d < HDIM; d++) s += eeb[d];
        sc[4] = s * (1.f / HDIM);
    }
}

// ew for all 3 layers in one edge_attr sweep
__global__ __launch_bounds__(256) void edge_weights_all(const float* __restrict__ edge_attr,
                                                        const float* __restrict__ wmean3,
                                                        const float* __restrict__ scal3,
                                                        float* __restrict__ ew3)
{
    int e = blockIdx.x * 4 + (threadIdx.x >> 6);
    int lane = threadIdx.x & 63;
    float a = edge_attr[(size_t)e * EDIM + lane];
    float v0 = a * wmean3[lane];
    float v1 = a * wmean3[64 + lane];
    float v2 = a * wmean3[128 + lane];
    #pragma unroll
    for (int off = 32; off > 0; off >>= 1) {
        v0 += __shfl_down(v0, off, 64);
        v1 += __shfl_down(v1, off, 64);
        v2 += __shfl_down(v2, off, 64);
    }
    if (lane == 0) {
        ew3[e] = v0 + scal3[4];
        ew3[N_EDGES + e] = v1 + scal3[12];
        ew3[2 * N_EDGES + e] = v2 + scal3[20];
    }
}

__global__ void loop_weights_all(const float* __restrict__ ew3, const int* __restrict__ row_ptr,
                                 const int* __restrict__ edge_ids, float* __restrict__ loopw3)
{
    int n = blockIdx.x * 256 + threadIdx.x;
    if (n >= N_NODES) return;
    int r0 = row_ptr[n], r1 = row_ptr[n + 1];
    float s0 = 0.f, s1 = 0.f, s2 = 0.f;
    for (int i = r0; i < r1; i++) {
        int e = edge_ids[i];
        s0 += ew3[e]; s1 += ew3[N_EDGES + e]; s2 += ew3[2 * N_EDGES + e];
    }
    float inv = 1.f / fmaxf((float)(r1 - r0), 1.f);
    loopw3[n] = s0 * inv;
    loopw3[N_NODES + n] = s1 * inv;
    loopw3[2 * N_NODES + n] = s2 * inv;
}

// a_s/a_d per node,head from bf16 xp
__global__ __launch_bounds__(256) void attn_coef(const unsigned short* __restrict__ xp,
                                                 const float* __restrict__ att_s,
                                                 const float* __restrict__ att_d,
                                                 float* __restrict__ a_s,
                                                 float* __restrict__ a_d)
{
    int n = blockIdx.x;
    int h = threadIdx.x >> 6;
    int lane = threadIdx.x & 63;
    ushort4 xv = *(const ushort4*)(xp + (size_t)n * NH + h * HDIM + lane * 4);
    float4 s4 = *(const float4*)(att_s + h * HDIM + lane * 4);
    float4 d4 = *(const float4*)(att_d + h * HDIM + lane * 4);
    float x0 = b2f(xv.x), x1 = b2f(xv.y), x2 = b2f(xv.z), x3 = b2f(xv.w);
    float ss = x0 * s4.x + x1 * s4.y + x2 * s4.z + x3 * s4.w;
    float sd = x0 * d4.x + x1 * d4.y + x2 * d4.z + x3 * d4.w;
    ss = wave_reduce_sum(ss);
    sd = wave_reduce_sum(sd);
    if (lane == 0) { a_s[n * 4 + h] = ss; a_d[n * 4 + h] = sd; }
}

// Fused segment-softmax + aggregate + head-mean + bias + LN + residual ReLU (in-place bf16 x)
__global__ __launch_bounds__(256) void gat_aggregate_ln(
    const unsigned short* __restrict__ xp, const float* __restrict__ a_s,
    const float* __restrict__ a_d, const float* __restrict__ ew,
    const float* __restrict__ loopw, const float* __restrict__ scal,
    const int* __restrict__ row_ptr, const int* __restrict__ edge_ids,
    const int* __restrict__ src0,
    const float* __restrict__ gat_b, const float* __restrict__ ln_g,
    const float* __restrict__ ln_b, unsigned short* __restrict__ x_bf)
{
    int n = blockIdx.x;
    int tid = threadIdx.x, lane = tid & 63, wid = tid >> 6;
    int r0 = row_ptr[n];
    int deg = row_ptr[n + 1] - r0;
    int cnt = deg + 1;

    __shared__ float c_sh[4], ad_sh[4], m_sh[4], s_sh[4];
    __shared__ float wred[4][8];
    __shared__ float p_ch[64 * 4];
    __shared__ int src_ch[64];
    __shared__ float lnred[4][2];
    __shared__ float musig[2];

    if (tid < 4) { c_sh[tid] = scal[tid]; ad_sh[tid] = a_d[n * 4 + tid]; }
    __syncthreads();

    // online softmax stats (merged max+sum pass)
    float m4[4], s4[4];
    #pragma unroll
    for (int h = 0; h < 4; h++) { m4[h] = -1e30f; s4[h] = 0.f; }
    for (int idx = tid; idx < cnt; idx += 256) {
        int sn; float w;
        if (idx < deg) { int e = edge_ids[r0 + idx]; sn = src0[e]; w = ew[e]; }
        else           { sn = n; w = loopw[n]; }
        #pragma unroll
        for (int h = 0; h < 4; h++) {
            float z = a_s[sn * 4 + h] + ad_sh[h] + c_sh[h] * w;
            z = z > 0.f ? z : 0.2f * z;
            float mn = fmaxf(m4[h], z);
            s4[h] = s4[h] * __expf(m4[h] - mn) + __expf(z - mn);
            m4[h] = mn;
        }
    }
    #pragma unroll
    for (int off = 32; off > 0; off >>= 1) {
        #pragma unroll
        for (int h = 0; h < 4; h++) {
            float mo = __shfl_down(m4[h], off, 64);
            float so = __shfl_down(s4[h], off, 64);
            float mn = fmaxf(m4[h], mo);
            s4[h] = s4[h] * __expf(m4[h] - mn) + so * __expf(mo - mn);
            m4[h] = mn;
        }
    }
    if (lane == 0) {
        #pragma unroll
        for (int h = 0; h < 4; h++) { wred[wid][h * 2] = m4[h]; wred[wid][h * 2 + 1] = s4[h]; }
    }
    __syncthreads();
    if (tid == 0) {
        #pragma unroll
        for (int h = 0; h < 4; h++) {
            float m = -1e30f, s = 0.f;
            #pragma unroll
            for (int w = 0; w < 4; w++) {
                float mw = wred[w][h * 2], sw = wred[w][h * 2 + 1];
                float mn = fmaxf(m, mw);
                s = s * __expf(m - mn) + sw * __expf(mw - mn);
                m = mn;
            }
            m_sh[h] = m;
            s_sh[h] = 1.f / s;
        }
    }
    __syncthreads();

    // weighted aggregation
    float acc = 0.f;
    int d = tid;
    for (int base = 0; base < cnt; base += 64) {
        int mcnt = min(64, cnt - base);
        if (tid < mcnt) {
            int idx = base + tid; int sn; float w;
            if (idx < deg) { int e = edge_ids[r0 + idx]; sn = src0[e]; w = ew[e]; }
            else           { sn = n; w = loopw[n]; }
            src_ch[tid] = sn;
            #pragma unroll
            for (int h = 0; h < 4; h++) {
                float z = a_s[sn * 4 + h] + ad_sh[h] + c_sh[h] * w;
                z = z > 0.f ? z : 0.2f * z;
                p_ch[tid * 4 + h] = __expf(z - m_sh[h]) * s_sh[h];
            }
        }
        __syncthreads();
        for (int j = 0; j < mcnt; j++) {
            const unsigned short* xr = xp + (size_t)src_ch[j] * NH + d;
            float4 pj = *(const float4*)(p_ch + j * 4);
            acc += pj.x * b2f(xr[0]) + pj.y * b2f(xr[256])
                 + pj.z * b2f(xr[512]) + pj.w * b2f(xr[768]);
        }
        __syncthreads();
    }

    float y = acc * 0.25f + gat_b[d];
    float s1 = y, s2 = y * y;
    #pragma unroll
    for (int off = 32; off > 0; off >>= 1) {
        s1 += __shfl_down(s1, off, 64);
        s2 += __shfl_down(s2, off, 64);
    }
    if (lane == 0) { lnred[wid][0] = s1; lnred[wid][1] = s2; }
    __syncthreads();
    if (tid == 0) {
        float t1 = lnred[0][0] + lnred[1][0] + lnred[2][0] + lnred[3][0];
        float t2 = lnred[0][1] + lnred[1][1] + lnred[2][1] + lnred[3][1];
        float mu = t1 * (1.f / HDIM);
        float var = t2 * (1.f / HDIM) - mu * mu;
        musig[0] = mu;
        musig[1] = rsqrtf(var + 1e-5f);
    }
    __syncthreads();
    float xn = ln_g[d] * (y - musig[0]) * musig[1] + ln_b[d];
    float xo = b2f(x_bf[(size_t)n * HDIM + d]);
    x_bf[(size_t)n * HDIM + d] = f2b(fmaxf(xo + xn, 0.f));
}

// head second layer from bf16 hmid [N][512]
__global__ __launch_bounds__(256) void head2_kernel(const unsigned short* __restrict__ hmid,
                                                    const float* __restrict__ w2,
                                                    const float* __restrict__ b2,
                                                    float* __restrict__ out)
{
    int gw = blockIdx.x * 4 + (threadIdx.x >> 6);
    int lane = threadIdx.x & 63;
    int n = gw >> 2;
    int k = gw & 3;
    const unsigned short* hr = hmid + (size_t)n * 512 + k * 128;
    const float* wr = w2 + k * 128;
    float s = b2f(hr[lane]) * wr[lane] + b2f(hr[lane + 64]) * wr[lane + 64];
    s = wave_reduce_sum(s);
    if (lane == 0) {
        s += b2[k];
        if (k == 0 || k == 3) s = 1.f / (1.f + __expf(-s));
        out[(size_t)k * N_NODES + n] = s;
    }
}

__global__ void copy_emb(const unsigned short* __restrict__ x_bf, float* __restrict__ out) {
    int i = blockIdx.x * 256 + threadIdx.x;
    ushort4 v = ((const ushort4*)x_bf)[i];
    float4 o = make_float4(b2f(v.x), b2f(v.y), b2f(v.z), b2f(v.w));
    ((float4*)out)[i] = o;
}

extern "C" void kernel_launch(void* const* d_in, const int* in_sizes, int n_in,
                              void* d_out, int out_size, void* d_ws, size_t ws_size,
                              hipStream_t stream) {
    const float* node_features = (const float*)d_in[0];
    const float* edge_attr     = (const float*)d_in[1];
    const float* enc_w         = (const float*)d_in[2];
    const float* enc_b         = (const float*)d_in[3];
    const float* edge_enc_w    = (const float*)d_in[4];
    const float* edge_enc_b    = (const float*)d_in[5];
    const float* gat_w         = (const float*)d_in[6];
    const float* att_src       = (const float*)d_in[7];
    const float* att_dst       = (const float*)d_in[8];
    const float* att_edge      = (const float*)d_in[9];
    const float* lin_edge_w    = (const float*)d_in[10];
    const float* gat_b         = (const float*)d_in[11];
    const float* ln_g          = (const float*)d_in[12];
    const float* ln_b          = (const float*)d_in[13];
    const float* head_w1       = (const float*)d_in[14];
    const float* head_b1       = (const float*)d_in[15];
    const float* head_w2       = (const float*)d_in[16];
    const float* head_b2       = (const float*)d_in[17];
    const int*   edge_index    = (const int*)d_in[18];
    const int* src0 = edge_index;
    const int* dst0 = edge_index + N_EDGES;
    float* out = (float*)d_out;

    // workspace layout (256B-aligned chunks)
    char* cur = (char*)d_ws;
    auto alloc = [&](size_t bytes) { char* p = cur; cur += (bytes + 255) & ~(size_t)255; return p; };
    unsigned short* x_bf   = (unsigned short*)alloc((size_t)N_NODES * HDIM * 2);
    unsigned short* xp_bf  = (unsigned short*)alloc((size_t)N_NODES * NH * 2);   // also hmid
    unsigned short* nf_bf  = (unsigned short*)alloc((size_t)N_NODES * NDIM * 2);
    unsigned short* enc_wt = (unsigned short*)alloc((size_t)HDIM * NDIM * 2);
    unsigned short* gat_wt = (unsigned short*)alloc((size_t)NLAYERS * NH * HDIM * 2);
    unsigned short* hw1t   = (unsigned short*)alloc((size_t)512 * HDIM * 2);
    float* a_s    = (float*)alloc((size_t)N_NODES * 4 * 4);
    float* a_d    = (float*)alloc((size_t)N_NODES * 4 * 4);
    float* ew3    = (float*)alloc((size_t)3 * N_EDGES * 4);
    float* loopw3 = (float*)alloc((size_t)3 * N_NODES * 4);
    float* wmean3 = (float*)alloc(192 * 4);
    float* scal3  = (float*)alloc(24 * 4);
    // cnt and fillc MUST be one contiguous block: a single memset covers both
    // exactly (256B-aligned alloc padding between separate allocs left fillc's
    // tail poisoned 0xAA -> OOB edge_ids writes -> R2 crash).
    int* cnt      = (int*)alloc((size_t)2 * N_NODES * 4);
    int* fillc    = cnt + N_NODES;
    int* row_ptr  = (int*)alloc((size_t)(N_NODES + 1) * 4);
    int* edge_ids = (int*)alloc((size_t)N_EDGES * 4);
    unsigned short* hmid = xp_bf;

    hipMemsetAsync(cnt, 0, (size_t)2 * N_NODES * sizeof(int), stream);

    // CSR build
    hist_kernel<<<(N_EDGES + 255) / 256, 256, 0, stream>>>(dst0, cnt);
    scan_kernel<<<1, 256, 0, stream>>>(cnt, row_ptr);
    fill_kernel<<<(N_EDGES + 255) / 256, 256, 0, stream>>>(dst0, row_ptr, fillc, edge_ids);

    // weight conversion
    conv_bf<<<(N_NODES * NDIM / 4) / 256, 256, 0, stream>>>(node_features, nf_bf);
    transpose_bf<<<dim3(HDIM / 32, NDIM / 32, 1), dim3(32, 8), 0, stream>>>(
        enc_w, enc_wt, NDIM, HDIM, 0, 0);
    transpose_bf<<<dim3(NH / 32, HDIM / 32, NLAYERS), dim3(32, 8), 0, stream>>>(
        gat_w, gat_wt, HDIM, NH, (size_t)HDIM * NH, (size_t)NH * HDIM);
    transpose_bf<<<dim3(128 / 32, HDIM / 32, 4), dim3(32, 8), 0, stream>>>(
        head_w1, hw1t, HDIM, 128, (size_t)HDIM * 128, (size_t)128 * HDIM);

    // edge scalar weights for all layers
    layer_prep3<<<3, 128, 0, stream>>>(edge_enc_w, edge_enc_b, lin_edge_w, att_edge, wmean3, scal3);
    edge_weights_all<<<N_EDGES / 4, 256, 0, stream>>>(edge_attr, wmean3, scal3, ew3);
    loop_weights_all<<<(N_NODES + 255) / 256, 256, 0, stream>>>(ew3, row_ptr, edge_ids, loopw3);

    // encoder: x = relu(nf @ enc_w + enc_b), bf16
    gemm_bf16<true, true><<<dim3(HDIM / 128, (N_NODES + 127) / 128), 256, 0, stream>>>(
        nf_bf, enc_wt, enc_b, x_bf, N_NODES, HDIM, NDIM);

    for (int l = 0; l < NLAYERS; l++) {
        gemm_bf16<false, false><<<dim3(NH / 128, (N_NODES + 127) / 128), 256, 0, stream>>>(
            x_bf, gat_wt + (size_t)l * NH * HDIM, nullptr, xp_bf, N_NODES, NH, HDIM);
        attn_coef<<<N_NODES, 256, 0, stream>>>(xp_bf, att_src + (size_t)l * NH,
                                               att_dst + (size_t)l * NH, a_s, a_d);
        gat_aggregate_ln<<<N_NODES, 256, 0, stream>>>(
            xp_bf, a_s, a_d, ew3 + (size_t)l * N_EDGES, loopw3 + (size_t)l * N_NODES,
            scal3 + l * 8, row_ptr, edge_ids, src0,
            gat_b + (size_t)l * HDIM, ln_g + (size_t)l * HDIM, ln_b + (size_t)l * HDIM, x_bf);
    }

    // fused 4-head first layer: hmid = relu(x @ W1 + b1), N=512
    gemm_bf16<true, true><<<dim3(512 / 128, (N_NODES + 127) / 128), 256, 0, stream>>>(
        x_bf, hw1t, head_b1, hmid, N_NODES, 512, HDIM);
    head2_kernel<<<N_NODES, 256, 0, stream>>>(hmid, head_w2, head_b2, out);

    copy_emb<<<(N_NODES * HDIM / 4) / 256, 256, 0, stream>>>(x_bf, out + 4 * N_NODES);
}